// Round 11
// baseline (5565.520 us; speedup 1.0000x reference)
//
#include <hip/hip_runtime.h>
#include <hip/hip_bf16.h>
#include <math.h>

#define N_DOC 4
#define C_    1024
#define D_    768
#define H_    12
#define E_    40
#define M_    3
#define P_    800
#define NP_   3200
#define EMB_  768
#define NREL_ 97
#define IN2_  1536   // 2*D
#define NPART 24     // 12 k-blocks x 2 b-halves

#define GLOAD_LDS16(g, l) \
  __builtin_amdgcn_global_load_lds( \
      (const __attribute__((address_space(1))) void*)(g), \
      (__attribute__((address_space(3))) void*)(l), 16, 0, 0)

// ---------------------------------------------------------------- A: ent_emb
__global__ void k_ent_emb(const float* __restrict__ seq, const int* __restrict__ mpos,
                          float* __restrict__ ent_emb) {
  int ne = blockIdx.x;                 // 0..159
  int n = ne / E_, e = ne % E_;
  int base = (n * E_ + e) * M_;
  int p0 = mpos[base + 0] + 1, p1 = mpos[base + 1] + 1, p2 = mpos[base + 2] + 1;
  const float* s0 = seq + ((size_t)n * C_ + p0) * D_;
  const float* s1 = seq + ((size_t)n * C_ + p1) * D_;
  const float* s2 = seq + ((size_t)n * C_ + p2) * D_;
  float* out = ent_emb + (size_t)ne * D_;
  for (int d = threadIdx.x; d < D_; d += blockDim.x) {
    double a = s0[d], b = s1[d], c = s2[d];
    double mx = fmax(a, fmax(b, c));
    double s = exp(a - mx) + exp(b - mx) + exp(c - mx);
    out[d] = (float)(mx + log(s));
  }
}

// ---------------------------------------------------------------- B: ent_att
__global__ void k_ent_att(const float* __restrict__ att, const int* __restrict__ mpos,
                          float* __restrict__ ent_att) {
  int idx = blockIdx.x * 256 + threadIdx.x;        // exactly N*E*H*C = 1966080
  int c = idx & (C_ - 1);
  int h = (idx >> 10) % H_;
  int rem = idx / (C_ * H_);
  int e = rem % E_;
  int n = rem / E_;
  int base = (n * E_ + e) * M_;
  float acc = 0.f;
#pragma unroll
  for (int m = 0; m < M_; ++m) {
    int p = mpos[base + m] + 1;
    acc += att[(((size_t)n * H_ + h) * C_ + p) * C_ + c];
  }
  ent_att[idx] = acc / 3.0f;
}

// ---------------------------------------------------------------- C: ht_att
__global__ void k_ht_att(const float* __restrict__ ent_att, const int* __restrict__ hts,
                         float* __restrict__ ht) {
  int np = blockIdx.x;                 // 0..3199
  int n = np / P_;
  int hi = hts[np * 2 + 0], ti = hts[np * 2 + 1];
  const float* ea_h = ent_att + (size_t)(n * E_ + hi) * H_ * C_;
  const float* ea_t = ent_att + (size_t)(n * E_ + ti) * H_ * C_;
  const int t = threadIdx.x;           // 0..63
  float4 v[4];
  float local = 0.f;
#pragma unroll
  for (int q = 0; q < 4; ++q) {
    int c = t * 4 + 256 * q;
    float4 a = {0.f, 0.f, 0.f, 0.f};
#pragma unroll
    for (int h = 0; h < H_; ++h) {
      float4 x = *(const float4*)(ea_h + (size_t)h * C_ + c);
      float4 y = *(const float4*)(ea_t + (size_t)h * C_ + c);
      a.x += x.x * y.x; a.y += x.y * y.y; a.z += x.z * y.z; a.w += x.w * y.w;
    }
    a.x /= 12.f; a.y /= 12.f; a.z /= 12.f; a.w /= 12.f;
    v[q] = a;
    local += a.x + a.y + a.z + a.w;
  }
  float s = local;
#pragma unroll
  for (int m = 32; m > 0; m >>= 1) s += __shfl_xor(s, m);
  float S = s + 1e-5f;
#pragma unroll
  for (int q = 0; q < 4; ++q) {
    int c = t * 4 + 256 * q;
    float4 o;
    o.x = v[q].x / S; o.y = v[q].y / S; o.z = v[q].z / S; o.w = v[q].w / S;
    *(float4*)&ht[(size_t)np * C_ + c] = o;
  }
}

// ---------------------------------------------------------------- D: rs GEMM
__global__ void k_rs(const float* __restrict__ ht, const float* __restrict__ seq,
                     float* __restrict__ rs) {
  const int pt0 = blockIdx.x * 16;     // 200 tiles
  const int n = pt0 / P_;
  const int ot = threadIdx.x & 63;
  const int jt = threadIdx.x >> 6;     // 0..3
  const int o4 = blockIdx.y * 256 + ot * 4;
  __shared__ float hlds[16 * 66];
  float4 a32[4];
  double a64[4][4];
#pragma unroll
  for (int q = 0; q < 4; ++q) {
    a32[q] = {0.f, 0.f, 0.f, 0.f};
#pragma unroll
    for (int i = 0; i < 4; ++i) a64[q][i] = 0.0;
  }
  const float* seqn = seq + (size_t)n * C_ * D_;
  for (int c0 = 0; c0 < C_; c0 += 64) {
    for (int l = threadIdx.x; l < 1024; l += 256) {
      int j = l >> 6, cc = l & 63;
      hlds[j * 66 + cc] = ht[(size_t)(pt0 + j) * C_ + c0 + cc];
    }
    __syncthreads();
#pragma unroll 4
    for (int cc = 0; cc < 64; ++cc) {
      float4 sv = *(const float4*)&seqn[(size_t)(c0 + cc) * D_ + o4];
#pragma unroll
      for (int q = 0; q < 4; ++q) {
        float w = hlds[(jt * 4 + q) * 66 + cc];
        a32[q].x += w * sv.x; a32[q].y += w * sv.y;
        a32[q].z += w * sv.z; a32[q].w += w * sv.w;
      }
    }
#pragma unroll
    for (int q = 0; q < 4; ++q) {
      a64[q][0] += (double)a32[q].x; a64[q][1] += (double)a32[q].y;
      a64[q][2] += (double)a32[q].z; a64[q][3] += (double)a32[q].w;
      a32[q] = {0.f, 0.f, 0.f, 0.f};
    }
    __syncthreads();
  }
#pragma unroll
  for (int q = 0; q < 4; ++q) {
    int p = pt0 + jt * 4 + q;
#pragma unroll
    for (int i = 0; i < 4; ++i)
      rs[(size_t)p * D_ + o4 + i] = (float)a64[q][i];
  }
}

// ---------------------------------------------------------------- E: zh / zt
__global__ void k_zht(const float* __restrict__ ent_emb, const float* __restrict__ rs,
                      const int* __restrict__ hts, const float* __restrict__ W,
                      const float* __restrict__ bias, float* __restrict__ out,
                      int which, int dbl_tanh) {
  const int pt0 = blockIdx.x * 16;
  const int n = pt0 / P_;
  const int ot = threadIdx.x & 63;
  const int jt = threadIdx.x >> 6;
  const int o4 = blockIdx.y * 256 + ot * 4;
  __shared__ float xlds[16 * 66];
  __shared__ int sidx[16];
  if (threadIdx.x < 16) sidx[threadIdx.x] = hts[(pt0 + threadIdx.x) * 2 + which];
  float4 a32[4];
  double a64[4][4];
#pragma unroll
  for (int q = 0; q < 4; ++q) {
    a32[q] = {0.f, 0.f, 0.f, 0.f};
#pragma unroll
    for (int i = 0; i < 4; ++i) a64[q][i] = 0.0;
  }
  __syncthreads();
  for (int k0 = 0; k0 < IN2_; k0 += 64) {
    for (int l = threadIdx.x; l < 1024; l += 256) {
      int j = l >> 6, q = l & 63;
      int kx = k0 + q;
      float val;
      if (kx < D_) val = ent_emb[(size_t)(n * E_ + sidx[j]) * D_ + kx];
      else         val = rs[(size_t)(pt0 + j) * D_ + (kx - D_)];
      xlds[j * 66 + q] = val;
    }
    __syncthreads();
#pragma unroll 4
    for (int q = 0; q < 64; ++q) {
      float4 wv = *(const float4*)&W[(size_t)(k0 + q) * EMB_ + o4];
#pragma unroll
      for (int j = 0; j < 4; ++j) {
        float x = xlds[(jt * 4 + j) * 66 + q];
        a32[j].x += x * wv.x; a32[j].y += x * wv.y;
        a32[j].z += x * wv.z; a32[j].w += x * wv.w;
      }
    }
#pragma unroll
    for (int j = 0; j < 4; ++j) {
      a64[j][0] += (double)a32[j].x; a64[j][1] += (double)a32[j].y;
      a64[j][2] += (double)a32[j].z; a64[j][3] += (double)a32[j].w;
      a32[j] = {0.f, 0.f, 0.f, 0.f};
    }
    __syncthreads();
  }
#pragma unroll
  for (int j = 0; j < 4; ++j) {
    int p = pt0 + jt * 4 + j;
#pragma unroll
    for (int i = 0; i < 4; ++i) {
      int o = o4 + i;
      double z = a64[j][i] + (double)bias[o];
      z = tanh(z);
      if (dbl_tanh) z = tanh(z);
      out[(size_t)p * EMB_ + o] = (float)z;
    }
  }
}

// ---------------------------------------------------------------- F: logits partial (all 97 r)
// Wave-supply round: j=4 pairs/thread -> 4800 waves total (4.7/SIMD demanded);
// single-buffer Wlin (24.8 KB -> 6 blk/CU cap, occupancy uncapped). 256-thread
// blocks, 64-pair tiles, 1200 blocks (= 24 slabs x 50 tiles, XCD affinity
// preserved). W staged via async global_load_lds; 2 barriers per b -- at 4.7
// waves/SIMD the barrier/staging stalls are hidden by cross-block overlap.
// Scalar FMA; per-output summation order (c asc within b, b asc) identical to
// rounds 4-10 -> partials bit-identical. r=96 folded in.
__global__ __launch_bounds__(256) void k_logits_part(
    const float* __restrict__ zh, const float* __restrict__ zt,
    const float* __restrict__ Wb, float* __restrict__ part) {
  const int bid = blockIdx.x;          // 0..1199
  const int s   = bid % 24;            // slab = k*2+bh  (XCD s%8 affinity)
  const int t   = bid / 24;            // p-tile 0..49
  const int k   = s >> 1, bh = s & 1;
  const int pt0 = t * 64;
  const int rt = threadIdx.x & 15;
  const int pg = threadIdx.x >> 4;     // 0..15 -> pairs pg*4+j
  const int kb0 = k * 64 + bh * 32;

  __shared__ float Wlin[64 * 97];      // 24832 B -> 6 blk/CU LDS cap

  // stage slice b (1552 float4 = 6 x 256 + 16 tail)
  auto stage_w = [&](int b) {
    const float* src = Wb + (size_t)(kb0 + b) * 6208;
#pragma unroll
    for (int u = 0; u < 6; ++u)
      GLOAD_LDS16(src + (u * 256 + threadIdx.x) * 4,
                  Wlin + (u * 256 + threadIdx.x) * 4);
    if (threadIdx.x < 16)
      GLOAD_LDS16(src + (1536 + threadIdx.x) * 4,
                  Wlin + (1536 + threadIdx.x) * 4);
  };

  stage_w(0);

  float acc[4][6];
  float acc6[4];
#pragma unroll
  for (int j = 0; j < 4; ++j) {
    acc6[j] = 0.f;
#pragma unroll
    for (int i = 0; i < 6; ++i) acc[j][i] = 0.f;
  }

  const float* ztb  = zt + (size_t)(pt0 + pg * 4) * EMB_ + k * 64;
  const float* zh_g = zh + (size_t)(pt0 + pg * 4) * EMB_ + kb0;

  __syncthreads();                     // drains vmcnt: Wlin(b=0) ready

  for (int b = 0; b < 32; ++b) {
    float zhv[4];
#pragma unroll
    for (int j = 0; j < 4; ++j) zhv[j] = zh_g[(size_t)j * EMB_ + b];

    for (int c0 = 0; c0 < 64; c0 += 4) {
      float4 ztv[4];
#pragma unroll
      for (int j = 0; j < 4; ++j)
        ztv[j] = *(const float4*)(ztb + (size_t)j * EMB_ + c0);
      float4 pz[4];
#pragma unroll
      for (int j = 0; j < 4; ++j) {
        pz[j].x = zhv[j] * ztv[j].x; pz[j].y = zhv[j] * ztv[j].y;
        pz[j].z = zhv[j] * ztv[j].z; pz[j].w = zhv[j] * ztv[j].w;
      }
#pragma unroll
      for (int cc = 0; cc < 4; ++cc) {
        const float* wr = &Wlin[(c0 + cc) * 97];
        float w6 = wr[96];
#pragma unroll
        for (int i = 0; i < 6; ++i) {
          float w = wr[rt + 16 * i];   // compiler ds_read_b32, 16-lane broadcast
#pragma unroll
          for (int j = 0; j < 4; ++j) {
            float pzc = (cc == 0) ? pz[j].x : (cc == 1) ? pz[j].y
                      : (cc == 2) ? pz[j].z : pz[j].w;
            acc[j][i] += pzc * w;
          }
        }
#pragma unroll
        for (int j = 0; j < 4; ++j) {
          float pzc = (cc == 0) ? pz[j].x : (cc == 1) ? pz[j].y
                    : (cc == 2) ? pz[j].z : pz[j].w;
          acc6[j] += pzc * w6;
        }
      }
    }
    if (b < 31) {
      __syncthreads();                 // readers of Wlin(b) done
      stage_w(b + 1);
      __syncthreads();                 // drains vmcnt: Wlin(b+1) ready
    }
  }

  float* po = part + (size_t)s * NP_ * NREL_;
#pragma unroll
  for (int j = 0; j < 4; ++j) {
    int p = pt0 + pg * 4 + j;
#pragma unroll
    for (int i = 0; i < 6; ++i)
      po[(size_t)p * NREL_ + rt + 16 * i] = acc[j][i];
    if (rt == 0) po[(size_t)p * NREL_ + 96] = acc6[j];
  }
}

// ---------------------------------------------------------------- G: finalize
__global__ void k_final(const float* __restrict__ part, const float* __restrict__ bb,
                        float* __restrict__ out) {
  const int p = blockIdx.x;
  const int r = threadIdx.x;           // 128 threads
  __shared__ double th_s;
  __shared__ int cnt[128];
  double v = 0.0;
  if (r < NREL_) {
#pragma unroll
    for (int g = 0; g < NPART; ++g)
      v += (double)part[(size_t)g * NP_ * NREL_ + (size_t)p * NREL_ + r];
    v += (double)bb[r];
    out[(size_t)p * NREL_ + r] = (float)v;
  }
  if (r == 0) th_s = v;
  __syncthreads();
  int pred = (r >= 1 && r < NREL_ && v > th_s) ? 1 : 0;
  cnt[r] = pred;
  __syncthreads();
  for (int s = 64; s > 0; s >>= 1) {
    if (r < s) cnt[r] += cnt[r + s];
    __syncthreads();
  }
  if (r < NREL_) {
    float pv = (r == 0) ? ((cnt[0] == 0) ? 1.f : 0.f) : (float)pred;
    out[(size_t)NP_ * NREL_ + (size_t)p * NREL_ + r] = pv;
  }
}

extern "C" void kernel_launch(void* const* d_in, const int* in_sizes, int n_in,
                              void* d_out, int out_size, void* d_ws, size_t ws_size,
                              hipStream_t stream) {
  const float* seq  = (const float*)d_in[0];
  const float* att  = (const float*)d_in[1];
  const int*   mpos = (const int*)d_in[2];
  const int*   hts  = (const int*)d_in[3];
  const float* Wh   = (const float*)d_in[4];
  const float* bh   = (const float*)d_in[5];
  const float* Wt   = (const float*)d_in[6];
  const float* bt   = (const float*)d_in[7];
  const float* Wb   = (const float*)d_in[8];
  const float* bb   = (const float*)d_in[9];
  float* out = (float*)d_out;
  float* ws = (float*)d_ws;

  float* ent_emb = ws;                   // [0, 122880)
  float* ent_att = ws + 122880;          // dead after k_ht_att
  float* ht      = ws + 2088960;         // dead after k_rs
  float* rs      = ws + 5365760;         // dead after k_zht
  float* zh      = ws + 7823360;
  float* zt      = ws + 10280960;
  // part (24*3200*97 floats) aliases dead ent_att+ht+rs: [122880, 7572480)
  float* part    = ws + 122880;

  k_ent_emb<<<160, 256, 0, stream>>>(seq, mpos, ent_emb);
  k_ent_att<<<7680, 256, 0, stream>>>(att, mpos, ent_att);
  k_ht_att<<<3200, 64, 0, stream>>>(ent_att, hts, ht);
  k_rs<<<dim3(200, 3), 256, 0, stream>>>(ht, seq, rs);
  k_zht<<<dim3(200, 3), 256, 0, stream>>>(ent_emb, rs, hts, Wh, bh, zh, 0, 1);
  k_zht<<<dim3(200, 3), 256, 0, stream>>>(ent_emb, rs, hts, Wt, bt, zt, 1, 0);
  k_logits_part<<<1200, 256, 0, stream>>>(zh, zt, Wb, part);
  k_final<<<3200, 128, 0, stream>>>(part, bb, out);
}

// Round 12
// 1386.424 us; speedup vs baseline: 4.0143x; 4.0143x over previous
//
#include <hip/hip_runtime.h>
#include <hip/hip_bf16.h>
#include <math.h>

#define N_DOC 4
#define C_    1024
#define D_    768
#define H_    12
#define E_    40
#define M_    3
#define P_    800
#define NP_   3200
#define EMB_  768
#define NREL_ 97
#define IN2_  1536   // 2*D
#define NPART 24     // 12 k-blocks x 2 b-halves

#define GLOAD_LDS16(g, l) \
  __builtin_amdgcn_global_load_lds( \
      (const __attribute__((address_space(1))) void*)(g), \
      (__attribute__((address_space(3))) void*)(l), 16, 0, 0)

// ---------------------------------------------------------------- A: ent_emb
__global__ void k_ent_emb(const float* __restrict__ seq, const int* __restrict__ mpos,
                          float* __restrict__ ent_emb) {
  int ne = blockIdx.x;                 // 0..159
  int n = ne / E_, e = ne % E_;
  int base = (n * E_ + e) * M_;
  int p0 = mpos[base + 0] + 1, p1 = mpos[base + 1] + 1, p2 = mpos[base + 2] + 1;
  const float* s0 = seq + ((size_t)n * C_ + p0) * D_;
  const float* s1 = seq + ((size_t)n * C_ + p1) * D_;
  const float* s2 = seq + ((size_t)n * C_ + p2) * D_;
  float* out = ent_emb + (size_t)ne * D_;
  for (int d = threadIdx.x; d < D_; d += blockDim.x) {
    double a = s0[d], b = s1[d], c = s2[d];
    double mx = fmax(a, fmax(b, c));
    double s = exp(a - mx) + exp(b - mx) + exp(c - mx);
    out[d] = (float)(mx + log(s));
  }
}

// ---------------------------------------------------------------- B: ent_att
__global__ void k_ent_att(const float* __restrict__ att, const int* __restrict__ mpos,
                          float* __restrict__ ent_att) {
  int idx = blockIdx.x * 256 + threadIdx.x;        // exactly N*E*H*C = 1966080
  int c = idx & (C_ - 1);
  int h = (idx >> 10) % H_;
  int rem = idx / (C_ * H_);
  int e = rem % E_;
  int n = rem / E_;
  int base = (n * E_ + e) * M_;
  float acc = 0.f;
#pragma unroll
  for (int m = 0; m < M_; ++m) {
    int p = mpos[base + m] + 1;
    acc += att[(((size_t)n * H_ + h) * C_ + p) * C_ + c];
  }
  ent_att[idx] = acc / 3.0f;
}

// ---------------------------------------------------------------- C: ht_att
__global__ void k_ht_att(const float* __restrict__ ent_att, const int* __restrict__ hts,
                         float* __restrict__ ht) {
  int np = blockIdx.x;                 // 0..3199
  int n = np / P_;
  int hi = hts[np * 2 + 0], ti = hts[np * 2 + 1];
  const float* ea_h = ent_att + (size_t)(n * E_ + hi) * H_ * C_;
  const float* ea_t = ent_att + (size_t)(n * E_ + ti) * H_ * C_;
  const int t = threadIdx.x;           // 0..63
  float4 v[4];
  float local = 0.f;
#pragma unroll
  for (int q = 0; q < 4; ++q) {
    int c = t * 4 + 256 * q;
    float4 a = {0.f, 0.f, 0.f, 0.f};
#pragma unroll
    for (int h = 0; h < H_; ++h) {
      float4 x = *(const float4*)(ea_h + (size_t)h * C_ + c);
      float4 y = *(const float4*)(ea_t + (size_t)h * C_ + c);
      a.x += x.x * y.x; a.y += x.y * y.y; a.z += x.z * y.z; a.w += x.w * y.w;
    }
    a.x /= 12.f; a.y /= 12.f; a.z /= 12.f; a.w /= 12.f;
    v[q] = a;
    local += a.x + a.y + a.z + a.w;
  }
  float s = local;
#pragma unroll
  for (int m = 32; m > 0; m >>= 1) s += __shfl_xor(s, m);
  float S = s + 1e-5f;
#pragma unroll
  for (int q = 0; q < 4; ++q) {
    int c = t * 4 + 256 * q;
    float4 o;
    o.x = v[q].x / S; o.y = v[q].y / S; o.z = v[q].z / S; o.w = v[q].w / S;
    *(float4*)&ht[(size_t)np * C_ + c] = o;
  }
}

// ---------------------------------------------------------------- D: rs GEMM
// 8-pair tiles, grid (400,3): 4800 waves (4.7/SIMD). Thread = 2p x 4o (float4).
// c-chunk boundaries unchanged -> rs bit-identical to prior rounds.
__global__ void k_rs(const float* __restrict__ ht, const float* __restrict__ seq,
                     float* __restrict__ rs) {
  const int pt0 = blockIdx.x * 8;      // 400 tiles
  const int n = pt0 / P_;
  const int ot = threadIdx.x & 63;
  const int jt = threadIdx.x >> 6;     // 0..3 -> pairs jt*2, jt*2+1
  const int o4 = blockIdx.y * 256 + ot * 4;
  __shared__ float hlds[8 * 66];
  float4 a32[2];
  double a64[2][4];
#pragma unroll
  for (int q = 0; q < 2; ++q) {
    a32[q] = {0.f, 0.f, 0.f, 0.f};
#pragma unroll
    for (int i = 0; i < 4; ++i) a64[q][i] = 0.0;
  }
  const float* seqn = seq + (size_t)n * C_ * D_;
  for (int c0 = 0; c0 < C_; c0 += 64) {
    for (int l = threadIdx.x; l < 512; l += 256) {
      int j = l >> 6, cc = l & 63;
      hlds[j * 66 + cc] = ht[(size_t)(pt0 + j) * C_ + c0 + cc];
    }
    __syncthreads();
#pragma unroll 4
    for (int cc = 0; cc < 64; ++cc) {
      float4 sv = *(const float4*)&seqn[(size_t)(c0 + cc) * D_ + o4];
#pragma unroll
      for (int q = 0; q < 2; ++q) {
        float w = hlds[(jt * 2 + q) * 66 + cc];
        a32[q].x += w * sv.x; a32[q].y += w * sv.y;
        a32[q].z += w * sv.z; a32[q].w += w * sv.w;
      }
    }
#pragma unroll
    for (int q = 0; q < 2; ++q) {
      a64[q][0] += (double)a32[q].x; a64[q][1] += (double)a32[q].y;
      a64[q][2] += (double)a32[q].z; a64[q][3] += (double)a32[q].w;
      a32[q] = {0.f, 0.f, 0.f, 0.f};
    }
    __syncthreads();
  }
#pragma unroll
  for (int q = 0; q < 2; ++q) {
    int p = pt0 + jt * 2 + q;
#pragma unroll
    for (int i = 0; i < 4; ++i)
      rs[(size_t)p * D_ + o4 + i] = (float)a64[q][i];
  }
}

// ---------------------------------------------------------------- E: zh / zt
// 8-pair tiles, grid (400,3): 4800 waves. Thread = 2p x 4o. k-chunk boundaries
// unchanged -> zh/zt bit-identical.
__global__ void k_zht(const float* __restrict__ ent_emb, const float* __restrict__ rs,
                      const int* __restrict__ hts, const float* __restrict__ W,
                      const float* __restrict__ bias, float* __restrict__ out,
                      int which, int dbl_tanh) {
  const int pt0 = blockIdx.x * 8;
  const int n = pt0 / P_;
  const int ot = threadIdx.x & 63;
  const int jt = threadIdx.x >> 6;     // 0..3 -> pairs jt*2, jt*2+1
  const int o4 = blockIdx.y * 256 + ot * 4;
  __shared__ float xlds[8 * 66];
  __shared__ int sidx[8];
  if (threadIdx.x < 8) sidx[threadIdx.x] = hts[(pt0 + threadIdx.x) * 2 + which];
  float4 a32[2];
  double a64[2][4];
#pragma unroll
  for (int q = 0; q < 2; ++q) {
    a32[q] = {0.f, 0.f, 0.f, 0.f};
#pragma unroll
    for (int i = 0; i < 4; ++i) a64[q][i] = 0.0;
  }
  __syncthreads();
  for (int k0 = 0; k0 < IN2_; k0 += 64) {
    for (int l = threadIdx.x; l < 512; l += 256) {
      int j = l >> 6, q = l & 63;
      int kx = k0 + q;
      float val;
      if (kx < D_) val = ent_emb[(size_t)(n * E_ + sidx[j]) * D_ + kx];
      else         val = rs[(size_t)(pt0 + j) * D_ + (kx - D_)];
      xlds[j * 66 + q] = val;
    }
    __syncthreads();
#pragma unroll 4
    for (int q = 0; q < 64; ++q) {
      float4 wv = *(const float4*)&W[(size_t)(k0 + q) * EMB_ + o4];
#pragma unroll
      for (int j = 0; j < 2; ++j) {
        float x = xlds[(jt * 2 + j) * 66 + q];
        a32[j].x += x * wv.x; a32[j].y += x * wv.y;
        a32[j].z += x * wv.z; a32[j].w += x * wv.w;
      }
    }
#pragma unroll
    for (int j = 0; j < 2; ++j) {
      a64[j][0] += (double)a32[j].x; a64[j][1] += (double)a32[j].y;
      a64[j][2] += (double)a32[j].z; a64[j][3] += (double)a32[j].w;
      a32[j] = {0.f, 0.f, 0.f, 0.f};
    }
    __syncthreads();
  }
#pragma unroll
  for (int j = 0; j < 2; ++j) {
    int p = pt0 + jt * 2 + j;
#pragma unroll
    for (int i = 0; i < 4; ++i) {
      int o = o4 + i;
      double z = a64[j][i] + (double)bias[o];
      z = tanh(z);
      if (dbl_tanh) z = tanh(z);
      out[(size_t)p * EMB_ + o] = (float)z;
    }
  }
}

// ---------------------------------------------------------------- F: logits partial (all 97 r)
// Wave-supply round, codegen-pinned: j=4 pairs/thread -> 4800 waves (4.7/SIMD);
// single-buffer Wlin (24.8 KB -> 6 blk/CU). #pragma unroll 1 on the c0 loop
// prevents the R11 pathology (full unroll + 64 hoisted float4 loads -> VGPR 256
// + scratch spill). Scalar FMA; per-output summation order (c asc within b,
// b asc) identical to rounds 4-10 -> partials bit-identical. r=96 folded in.
__global__ __launch_bounds__(256) void k_logits_part(
    const float* __restrict__ zh, const float* __restrict__ zt,
    const float* __restrict__ Wb, float* __restrict__ part) {
  const int bid = blockIdx.x;          // 0..1199
  const int s   = bid % 24;            // slab = k*2+bh  (XCD s%8 affinity)
  const int t   = bid / 24;            // p-tile 0..49
  const int k   = s >> 1, bh = s & 1;
  const int pt0 = t * 64;
  const int rt = threadIdx.x & 15;
  const int pg = threadIdx.x >> 4;     // 0..15 -> pairs pg*4+j
  const int kb0 = k * 64 + bh * 32;

  __shared__ float Wlin[64 * 97];      // 24832 B -> 6 blk/CU LDS cap

  // stage slice b (1552 float4 = 6 x 256 + 16 tail)
  auto stage_w = [&](int b) {
    const float* src = Wb + (size_t)(kb0 + b) * 6208;
#pragma unroll
    for (int u = 0; u < 6; ++u)
      GLOAD_LDS16(src + (u * 256 + threadIdx.x) * 4,
                  Wlin + (u * 256 + threadIdx.x) * 4);
    if (threadIdx.x < 16)
      GLOAD_LDS16(src + (1536 + threadIdx.x) * 4,
                  Wlin + (1536 + threadIdx.x) * 4);
  };

  stage_w(0);

  float acc[4][6];
  float acc6[4];
#pragma unroll
  for (int j = 0; j < 4; ++j) {
    acc6[j] = 0.f;
#pragma unroll
    for (int i = 0; i < 6; ++i) acc[j][i] = 0.f;
  }

  const float* ztb  = zt + (size_t)(pt0 + pg * 4) * EMB_ + k * 64;
  const float* zh_g = zh + (size_t)(pt0 + pg * 4) * EMB_ + kb0;

  __syncthreads();                     // drains vmcnt: Wlin(b=0) ready

#pragma unroll 1
  for (int b = 0; b < 32; ++b) {
    float zhv[4];
#pragma unroll
    for (int j = 0; j < 4; ++j) zhv[j] = zh_g[(size_t)j * EMB_ + b];

#pragma unroll 1
    for (int c0 = 0; c0 < 64; c0 += 4) {
      float4 ztv[4];
#pragma unroll
      for (int j = 0; j < 4; ++j)
        ztv[j] = *(const float4*)(ztb + (size_t)j * EMB_ + c0);
      float4 pz[4];
#pragma unroll
      for (int j = 0; j < 4; ++j) {
        pz[j].x = zhv[j] * ztv[j].x; pz[j].y = zhv[j] * ztv[j].y;
        pz[j].z = zhv[j] * ztv[j].z; pz[j].w = zhv[j] * ztv[j].w;
      }
#pragma unroll
      for (int cc = 0; cc < 4; ++cc) {
        const float* wr = &Wlin[(c0 + cc) * 97];
        float w6 = wr[96];
#pragma unroll
        for (int i = 0; i < 6; ++i) {
          float w = wr[rt + 16 * i];   // compiler ds_read_b32, 16-lane broadcast
#pragma unroll
          for (int j = 0; j < 4; ++j) {
            float pzc = (cc == 0) ? pz[j].x : (cc == 1) ? pz[j].y
                      : (cc == 2) ? pz[j].z : pz[j].w;
            acc[j][i] += pzc * w;
          }
        }
#pragma unroll
        for (int j = 0; j < 4; ++j) {
          float pzc = (cc == 0) ? pz[j].x : (cc == 1) ? pz[j].y
                    : (cc == 2) ? pz[j].z : pz[j].w;
          acc6[j] += pzc * w6;
        }
      }
    }
    if (b < 31) {
      __syncthreads();                 // readers of Wlin(b) done
      stage_w(b + 1);
      __syncthreads();                 // drains vmcnt: Wlin(b+1) ready
    }
  }

  float* po = part + (size_t)s * NP_ * NREL_;
#pragma unroll
  for (int j = 0; j < 4; ++j) {
    int p = pt0 + pg * 4 + j;
#pragma unroll
    for (int i = 0; i < 6; ++i)
      po[(size_t)p * NREL_ + rt + 16 * i] = acc[j][i];
    if (rt == 0) po[(size_t)p * NREL_ + 96] = acc6[j];
  }
}

// ---------------------------------------------------------------- G: finalize
__global__ void k_final(const float* __restrict__ part, const float* __restrict__ bb,
                        float* __restrict__ out) {
  const int p = blockIdx.x;
  const int r = threadIdx.x;           // 128 threads
  __shared__ double th_s;
  __shared__ int cnt[128];
  double v = 0.0;
  if (r < NREL_) {
#pragma unroll
    for (int g = 0; g < NPART; ++g)
      v += (double)part[(size_t)g * NP_ * NREL_ + (size_t)p * NREL_ + r];
    v += (double)bb[r];
    out[(size_t)p * NREL_ + r] = (float)v;
  }
  if (r == 0) th_s = v;
  __syncthreads();
  int pred = (r >= 1 && r < NREL_ && v > th_s) ? 1 : 0;
  cnt[r] = pred;
  __syncthreads();
  for (int s = 64; s > 0; s >>= 1) {
    if (r < s) cnt[r] += cnt[r + s];
    __syncthreads();
  }
  if (r < NREL_) {
    float pv = (r == 0) ? ((cnt[0] == 0) ? 1.f : 0.f) : (float)pred;
    out[(size_t)NP_ * NREL_ + (size_t)p * NREL_ + r] = pv;
  }
}

extern "C" void kernel_launch(void* const* d_in, const int* in_sizes, int n_in,
                              void* d_out, int out_size, void* d_ws, size_t ws_size,
                              hipStream_t stream) {
  const float* seq  = (const float*)d_in[0];
  const float* att  = (const float*)d_in[1];
  const int*   mpos = (const int*)d_in[2];
  const int*   hts  = (const int*)d_in[3];
  const float* Wh   = (const float*)d_in[4];
  const float* bh   = (const float*)d_in[5];
  const float* Wt   = (const float*)d_in[6];
  const float* bt   = (const float*)d_in[7];
  const float* Wb   = (const float*)d_in[8];
  const float* bb   = (const float*)d_in[9];
  float* out = (float*)d_out;
  float* ws = (float*)d_ws;

  float* ent_emb = ws;                   // [0, 122880)
  float* ent_att = ws + 122880;          // dead after k_ht_att
  float* ht      = ws + 2088960;         // dead after k_rs
  float* rs      = ws + 5365760;         // dead after k_zht
  float* zh      = ws + 7823360;
  float* zt      = ws + 10280960;
  // part (24*3200*97 floats) aliases dead ent_att+ht+rs: [122880, 7572480)
  float* part    = ws + 122880;

  k_ent_emb<<<160, 256, 0, stream>>>(seq, mpos, ent_emb);
  k_ent_att<<<7680, 256, 0, stream>>>(att, mpos, ent_att);
  k_ht_att<<<3200, 64, 0, stream>>>(ent_att, hts, ht);
  k_rs<<<dim3(400, 3), 256, 0, stream>>>(ht, seq, rs);
  k_zht<<<dim3(400, 3), 256, 0, stream>>>(ent_emb, rs, hts, Wh, bh, zh, 0, 1);
  k_zht<<<dim3(400, 3), 256, 0, stream>>>(ent_emb, rs, hts, Wt, bt, zt, 1, 0);
  k_logits_part<<<1200, 256, 0, stream>>>(zh, zt, Wb, part);
  k_final<<<3200, 128, 0, stream>>>(part, bb, out);
}

// Round 13
// 1119.670 us; speedup vs baseline: 4.9707x; 1.2382x over previous
//
#include <hip/hip_runtime.h>
#include <hip/hip_bf16.h>
#include <math.h>

#define N_DOC 4
#define C_    1024
#define D_    768
#define H_    12
#define E_    40
#define M_    3
#define P_    800
#define NP_   3200
#define EMB_  768
#define NREL_ 97
#define IN2_  1536   // 2*D
#define NPART 24     // 12 k-blocks x 2 b-halves

#define GLOAD_LDS16(g, l) \
  __builtin_amdgcn_global_load_lds( \
      (const __attribute__((address_space(1))) void*)(g), \
      (__attribute__((address_space(3))) void*)(l), 16, 0, 0)

// ---------------------------------------------------------------- A: ent_emb
__global__ void k_ent_emb(const float* __restrict__ seq, const int* __restrict__ mpos,
                          float* __restrict__ ent_emb) {
  int ne = blockIdx.x;                 // 0..159
  int n = ne / E_, e = ne % E_;
  int base = (n * E_ + e) * M_;
  int p0 = mpos[base + 0] + 1, p1 = mpos[base + 1] + 1, p2 = mpos[base + 2] + 1;
  const float* s0 = seq + ((size_t)n * C_ + p0) * D_;
  const float* s1 = seq + ((size_t)n * C_ + p1) * D_;
  const float* s2 = seq + ((size_t)n * C_ + p2) * D_;
  float* out = ent_emb + (size_t)ne * D_;
  for (int d = threadIdx.x; d < D_; d += blockDim.x) {
    double a = s0[d], b = s1[d], c = s2[d];
    double mx = fmax(a, fmax(b, c));
    double s = exp(a - mx) + exp(b - mx) + exp(c - mx);
    out[d] = (float)(mx + log(s));
  }
}

// ---------------------------------------------------------------- B: ent_att
__global__ void k_ent_att(const float* __restrict__ att, const int* __restrict__ mpos,
                          float* __restrict__ ent_att) {
  int idx = blockIdx.x * 256 + threadIdx.x;        // exactly N*E*H*C = 1966080
  int c = idx & (C_ - 1);
  int h = (idx >> 10) % H_;
  int rem = idx / (C_ * H_);
  int e = rem % E_;
  int n = rem / E_;
  int base = (n * E_ + e) * M_;
  float acc = 0.f;
#pragma unroll
  for (int m = 0; m < M_; ++m) {
    int p = mpos[base + m] + 1;
    acc += att[(((size_t)n * H_ + h) * C_ + p) * C_ + c];
  }
  ent_att[idx] = acc / 3.0f;
}

// ---------------------------------------------------------------- C: ht_att
__global__ void k_ht_att(const float* __restrict__ ent_att, const int* __restrict__ hts,
                         float* __restrict__ ht) {
  int np = blockIdx.x;                 // 0..3199
  int n = np / P_;
  int hi = hts[np * 2 + 0], ti = hts[np * 2 + 1];
  const float* ea_h = ent_att + (size_t)(n * E_ + hi) * H_ * C_;
  const float* ea_t = ent_att + (size_t)(n * E_ + ti) * H_ * C_;
  const int t = threadIdx.x;           // 0..63
  float4 v[4];
  float local = 0.f;
#pragma unroll
  for (int q = 0; q < 4; ++q) {
    int c = t * 4 + 256 * q;
    float4 a = {0.f, 0.f, 0.f, 0.f};
#pragma unroll
    for (int h = 0; h < H_; ++h) {
      float4 x = *(const float4*)(ea_h + (size_t)h * C_ + c);
      float4 y = *(const float4*)(ea_t + (size_t)h * C_ + c);
      a.x += x.x * y.x; a.y += x.y * y.y; a.z += x.z * y.z; a.w += x.w * y.w;
    }
    a.x /= 12.f; a.y /= 12.f; a.z /= 12.f; a.w /= 12.f;
    v[q] = a;
    local += a.x + a.y + a.z + a.w;
  }
  float s = local;
#pragma unroll
  for (int m = 32; m > 0; m >>= 1) s += __shfl_xor(s, m);
  float S = s + 1e-5f;
#pragma unroll
  for (int q = 0; q < 4; ++q) {
    int c = t * 4 + 256 * q;
    float4 o;
    o.x = v[q].x / S; o.y = v[q].y / S; o.z = v[q].z / S; o.w = v[q].w / S;
    *(float4*)&ht[(size_t)np * C_ + c] = o;
  }
}

// ---------------------------------------------------------------- D: rs GEMM (R10 form)
__global__ void k_rs(const float* __restrict__ ht, const float* __restrict__ seq,
                     float* __restrict__ rs) {
  const int pt0 = blockIdx.x * 16;     // 200 tiles
  const int n = pt0 / P_;
  const int ot = threadIdx.x & 63;
  const int jt = threadIdx.x >> 6;     // 0..3
  const int o4 = blockIdx.y * 256 + ot * 4;
  __shared__ float hlds[16 * 66];
  float4 a32[4];
  double a64[4][4];
#pragma unroll
  for (int q = 0; q < 4; ++q) {
    a32[q] = {0.f, 0.f, 0.f, 0.f};
#pragma unroll
    for (int i = 0; i < 4; ++i) a64[q][i] = 0.0;
  }
  const float* seqn = seq + (size_t)n * C_ * D_;
  for (int c0 = 0; c0 < C_; c0 += 64) {
    for (int l = threadIdx.x; l < 1024; l += 256) {
      int j = l >> 6, cc = l & 63;
      hlds[j * 66 + cc] = ht[(size_t)(pt0 + j) * C_ + c0 + cc];
    }
    __syncthreads();
#pragma unroll 4
    for (int cc = 0; cc < 64; ++cc) {
      float4 sv = *(const float4*)&seqn[(size_t)(c0 + cc) * D_ + o4];
#pragma unroll
      for (int q = 0; q < 4; ++q) {
        float w = hlds[(jt * 4 + q) * 66 + cc];
        a32[q].x += w * sv.x; a32[q].y += w * sv.y;
        a32[q].z += w * sv.z; a32[q].w += w * sv.w;
      }
    }
#pragma unroll
    for (int q = 0; q < 4; ++q) {
      a64[q][0] += (double)a32[q].x; a64[q][1] += (double)a32[q].y;
      a64[q][2] += (double)a32[q].z; a64[q][3] += (double)a32[q].w;
      a32[q] = {0.f, 0.f, 0.f, 0.f};
    }
    __syncthreads();
  }
#pragma unroll
  for (int q = 0; q < 4; ++q) {
    int p = pt0 + jt * 4 + q;
#pragma unroll
    for (int i = 0; i < 4; ++i)
      rs[(size_t)p * D_ + o4 + i] = (float)a64[q][i];
  }
}

// ---------------------------------------------------------------- E: zh / zt (R10 form)
__global__ void k_zht(const float* __restrict__ ent_emb, const float* __restrict__ rs,
                      const int* __restrict__ hts, const float* __restrict__ W,
                      const float* __restrict__ bias, float* __restrict__ out,
                      int which, int dbl_tanh) {
  const int pt0 = blockIdx.x * 16;
  const int n = pt0 / P_;
  const int ot = threadIdx.x & 63;
  const int jt = threadIdx.x >> 6;
  const int o4 = blockIdx.y * 256 + ot * 4;
  __shared__ float xlds[16 * 66];
  __shared__ int sidx[16];
  if (threadIdx.x < 16) sidx[threadIdx.x] = hts[(pt0 + threadIdx.x) * 2 + which];
  float4 a32[4];
  double a64[4][4];
#pragma unroll
  for (int q = 0; q < 4; ++q) {
    a32[q] = {0.f, 0.f, 0.f, 0.f};
#pragma unroll
    for (int i = 0; i < 4; ++i) a64[q][i] = 0.0;
  }
  __syncthreads();
  for (int k0 = 0; k0 < IN2_; k0 += 64) {
    for (int l = threadIdx.x; l < 1024; l += 256) {
      int j = l >> 6, q = l & 63;
      int kx = k0 + q;
      float val;
      if (kx < D_) val = ent_emb[(size_t)(n * E_ + sidx[j]) * D_ + kx];
      else         val = rs[(size_t)(pt0 + j) * D_ + (kx - D_)];
      xlds[j * 66 + q] = val;
    }
    __syncthreads();
#pragma unroll 4
    for (int q = 0; q < 64; ++q) {
      float4 wv = *(const float4*)&W[(size_t)(k0 + q) * EMB_ + o4];
#pragma unroll
      for (int j = 0; j < 4; ++j) {
        float x = xlds[(jt * 4 + j) * 66 + q];
        a32[j].x += x * wv.x; a32[j].y += x * wv.y;
        a32[j].z += x * wv.z; a32[j].w += x * wv.w;
      }
    }
#pragma unroll
    for (int j = 0; j < 4; ++j) {
      a64[j][0] += (double)a32[j].x; a64[j][1] += (double)a32[j].y;
      a64[j][2] += (double)a32[j].z; a64[j][3] += (double)a32[j].w;
      a32[j] = {0.f, 0.f, 0.f, 0.f};
    }
    __syncthreads();
  }
#pragma unroll
  for (int j = 0; j < 4; ++j) {
    int p = pt0 + jt * 4 + j;
#pragma unroll
    for (int i = 0; i < 4; ++i) {
      int o = o4 + i;
      double z = a64[j][i] + (double)bias[o];
      z = tanh(z);
      if (dbl_tanh) z = tanh(z);
      out[(size_t)p * EMB_ + o] = (float)z;
    }
  }
}

// ---------------------------------------------------------------- F: logits partial (all 97 r)
// j=4 pairs/thread (4800 waves) + double-buffered Wlin + ONE barrier per b:
// stage(b+1 -> other buffer) issued BEFORE compute(b), DMA flies under ~4K
// cycles of FMA; barrier at end of b drains vmcnt + guards buffer reuse
// (R10-proven structure). #pragma unroll 1 pins codegen (R11 pathology).
// Scalar FMA; per-output summation order (c asc within b, b asc) identical
// to rounds 4-12 -> partials bit-identical. r=96 folded in.
__global__ __launch_bounds__(256) void k_logits_part(
    const float* __restrict__ zh, const float* __restrict__ zt,
    const float* __restrict__ Wb, float* __restrict__ part) {
  const int bid = blockIdx.x;          // 0..1199
  const int s   = bid % 24;            // slab = k*2+bh  (XCD s%8 affinity)
  const int t   = bid / 24;            // p-tile 0..49
  const int k   = s >> 1, bh = s & 1;
  const int pt0 = t * 64;
  const int rt = threadIdx.x & 15;
  const int pg = threadIdx.x >> 4;     // 0..15 -> pairs pg*4+j
  const int kb0 = k * 64 + bh * 32;

  __shared__ float Wlin[2][64 * 97];   // 2 x 24832 B -> 49664 B, 3 blk/CU

  // stage slice b into buffer buf (1552 float4 = 6 x 256 + 16 tail)
  auto stage_w = [&](int buf, int b) {
    const float* src = Wb + (size_t)(kb0 + b) * 6208;
    float* dst = Wlin[buf];
#pragma unroll
    for (int u = 0; u < 6; ++u)
      GLOAD_LDS16(src + (u * 256 + threadIdx.x) * 4,
                  dst + (u * 256 + threadIdx.x) * 4);
    if (threadIdx.x < 16)
      GLOAD_LDS16(src + (1536 + threadIdx.x) * 4,
                  dst + (1536 + threadIdx.x) * 4);
  };

  stage_w(0, 0);

  float acc[4][6];
  float acc6[4];
#pragma unroll
  for (int j = 0; j < 4; ++j) {
    acc6[j] = 0.f;
#pragma unroll
    for (int i = 0; i < 6; ++i) acc[j][i] = 0.f;
  }

  const float* ztb  = zt + (size_t)(pt0 + pg * 4) * EMB_ + k * 64;
  const float* zh_g = zh + (size_t)(pt0 + pg * 4) * EMB_ + kb0;

  __syncthreads();                     // drains vmcnt: Wlin[0](b=0) ready

  int cur = 0;
#pragma unroll 1
  for (int b = 0; b < 32; ++b) {
    if (b < 31) stage_w(cur ^ 1, b + 1);   // async, overlaps compute(b)

    float zhv[4];
#pragma unroll
    for (int j = 0; j < 4; ++j) zhv[j] = zh_g[(size_t)j * EMB_ + b];

    const float* Wcur = Wlin[cur];
#pragma unroll 1
    for (int c0 = 0; c0 < 64; c0 += 4) {
      float4 ztv[4];
#pragma unroll
      for (int j = 0; j < 4; ++j)
        ztv[j] = *(const float4*)(ztb + (size_t)j * EMB_ + c0);
      float4 pz[4];
#pragma unroll
      for (int j = 0; j < 4; ++j) {
        pz[j].x = zhv[j] * ztv[j].x; pz[j].y = zhv[j] * ztv[j].y;
        pz[j].z = zhv[j] * ztv[j].z; pz[j].w = zhv[j] * ztv[j].w;
      }
#pragma unroll
      for (int cc = 0; cc < 4; ++cc) {
        const float* wr = &Wcur[(c0 + cc) * 97];
        float w6 = wr[96];
#pragma unroll
        for (int i = 0; i < 6; ++i) {
          float w = wr[rt + 16 * i];   // compiler ds_read_b32, 16-lane broadcast
#pragma unroll
          for (int j = 0; j < 4; ++j) {
            float pzc = (cc == 0) ? pz[j].x : (cc == 1) ? pz[j].y
                      : (cc == 2) ? pz[j].z : pz[j].w;
            acc[j][i] += pzc * w;
          }
        }
#pragma unroll
        for (int j = 0; j < 4; ++j) {
          float pzc = (cc == 0) ? pz[j].x : (cc == 1) ? pz[j].y
                    : (cc == 2) ? pz[j].z : pz[j].w;
          acc6[j] += pzc * w6;
        }
      }
    }
    __syncthreads();                   // readers of cur done + next slice landed
    cur ^= 1;
  }

  float* po = part + (size_t)s * NP_ * NREL_;
#pragma unroll
  for (int j = 0; j < 4; ++j) {
    int p = pt0 + pg * 4 + j;
#pragma unroll
    for (int i = 0; i < 6; ++i)
      po[(size_t)p * NREL_ + rt + 16 * i] = acc[j][i];
    if (rt == 0) po[(size_t)p * NREL_ + 96] = acc6[j];
  }
}

// ---------------------------------------------------------------- G: finalize
__global__ void k_final(const float* __restrict__ part, const float* __restrict__ bb,
                        float* __restrict__ out) {
  const int p = blockIdx.x;
  const int r = threadIdx.x;           // 128 threads
  __shared__ double th_s;
  __shared__ int cnt[128];
  double v = 0.0;
  if (r < NREL_) {
#pragma unroll
    for (int g = 0; g < NPART; ++g)
      v += (double)part[(size_t)g * NP_ * NREL_ + (size_t)p * NREL_ + r];
    v += (double)bb[r];
    out[(size_t)p * NREL_ + r] = (float)v;
  }
  if (r == 0) th_s = v;
  __syncthreads();
  int pred = (r >= 1 && r < NREL_ && v > th_s) ? 1 : 0;
  cnt[r] = pred;
  __syncthreads();
  for (int s = 64; s > 0; s >>= 1) {
    if (r < s) cnt[r] += cnt[r + s];
    __syncthreads();
  }
  if (r < NREL_) {
    float pv = (r == 0) ? ((cnt[0] == 0) ? 1.f : 0.f) : (float)pred;
    out[(size_t)NP_ * NREL_ + (size_t)p * NREL_ + r] = pv;
  }
}

extern "C" void kernel_launch(void* const* d_in, const int* in_sizes, int n_in,
                              void* d_out, int out_size, void* d_ws, size_t ws_size,
                              hipStream_t stream) {
  const float* seq  = (const float*)d_in[0];
  const float* att  = (const float*)d_in[1];
  const int*   mpos = (const int*)d_in[2];
  const int*   hts  = (const int*)d_in[3];
  const float* Wh   = (const float*)d_in[4];
  const float* bh   = (const float*)d_in[5];
  const float* Wt   = (const float*)d_in[6];
  const float* bt   = (const float*)d_in[7];
  const float* Wb   = (const float*)d_in[8];
  const float* bb   = (const float*)d_in[9];
  float* out = (float*)d_out;
  float* ws = (float*)d_ws;

  float* ent_emb = ws;                   // [0, 122880)
  float* ent_att = ws + 122880;          // dead after k_ht_att
  float* ht      = ws + 2088960;         // dead after k_rs
  float* rs      = ws + 5365760;         // dead after k_zht
  float* zh      = ws + 7823360;
  float* zt      = ws + 10280960;
  // part (24*3200*97 floats) aliases dead ent_att+ht+rs: [122880, 7572480)
  float* part    = ws + 122880;

  k_ent_emb<<<160, 256, 0, stream>>>(seq, mpos, ent_emb);
  k_ent_att<<<7680, 256, 0, stream>>>(att, mpos, ent_att);
  k_ht_att<<<3200, 64, 0, stream>>>(ent_att, hts, ht);
  k_rs<<<dim3(200, 3), 256, 0, stream>>>(ht, seq, rs);
  k_zht<<<dim3(200, 3), 256, 0, stream>>>(ent_emb, rs, hts, Wh, bh, zh, 0, 1);
  k_zht<<<dim3(200, 3), 256, 0, stream>>>(ent_emb, rs, hts, Wt, bt, zt, 1, 0);
  k_logits_part<<<1200, 256, 0, stream>>>(zh, zt, Wb, part);
  k_final<<<3200, 128, 0, stream>>>(part, bb, out);
}

// Round 14
// 1093.426 us; speedup vs baseline: 5.0900x; 1.0240x over previous
//
#include <hip/hip_runtime.h>
#include <hip/hip_bf16.h>
#include <math.h>

#define N_DOC 4
#define C_    1024
#define D_    768
#define H_    12
#define E_    40
#define M_    3
#define P_    800
#define NP_   3200
#define EMB_  768
#define NREL_ 97
#define IN2_  1536   // 2*D
#define NPART 24     // 12 k-blocks x 2 b-halves

#define GLOAD_LDS16(g, l) \
  __builtin_amdgcn_global_load_lds( \
      (const __attribute__((address_space(1))) void*)(g), \
      (__attribute__((address_space(3))) void*)(l), 16, 0, 0)

// ---------------------------------------------------------------- A: ent_emb
__global__ void k_ent_emb(const float* __restrict__ seq, const int* __restrict__ mpos,
                          float* __restrict__ ent_emb) {
  int ne = blockIdx.x;                 // 0..159
  int n = ne / E_, e = ne % E_;
  int base = (n * E_ + e) * M_;
  int p0 = mpos[base + 0] + 1, p1 = mpos[base + 1] + 1, p2 = mpos[base + 2] + 1;
  const float* s0 = seq + ((size_t)n * C_ + p0) * D_;
  const float* s1 = seq + ((size_t)n * C_ + p1) * D_;
  const float* s2 = seq + ((size_t)n * C_ + p2) * D_;
  float* out = ent_emb + (size_t)ne * D_;
  for (int d = threadIdx.x; d < D_; d += blockDim.x) {
    double a = s0[d], b = s1[d], c = s2[d];
    double mx = fmax(a, fmax(b, c));
    double s = exp(a - mx) + exp(b - mx) + exp(c - mx);
    out[d] = (float)(mx + log(s));
  }
}

// ---------------------------------------------------------------- B: ent_att
__global__ void k_ent_att(const float* __restrict__ att, const int* __restrict__ mpos,
                          float* __restrict__ ent_att) {
  int idx = blockIdx.x * 256 + threadIdx.x;        // exactly N*E*H*C = 1966080
  int c = idx & (C_ - 1);
  int h = (idx >> 10) % H_;
  int rem = idx / (C_ * H_);
  int e = rem % E_;
  int n = rem / E_;
  int base = (n * E_ + e) * M_;
  float acc = 0.f;
#pragma unroll
  for (int m = 0; m < M_; ++m) {
    int p = mpos[base + m] + 1;
    acc += att[(((size_t)n * H_ + h) * C_ + p) * C_ + c];
  }
  ent_att[idx] = acc / 3.0f;
}

// ---------------------------------------------------------------- C: ht_att
__global__ void k_ht_att(const float* __restrict__ ent_att, const int* __restrict__ hts,
                         float* __restrict__ ht) {
  int np = blockIdx.x;                 // 0..3199
  int n = np / P_;
  int hi = hts[np * 2 + 0], ti = hts[np * 2 + 1];
  const float* ea_h = ent_att + (size_t)(n * E_ + hi) * H_ * C_;
  const float* ea_t = ent_att + (size_t)(n * E_ + ti) * H_ * C_;
  const int t = threadIdx.x;           // 0..63
  float4 v[4];
  float local = 0.f;
#pragma unroll
  for (int q = 0; q < 4; ++q) {
    int c = t * 4 + 256 * q;
    float4 a = {0.f, 0.f, 0.f, 0.f};
#pragma unroll
    for (int h = 0; h < H_; ++h) {
      float4 x = *(const float4*)(ea_h + (size_t)h * C_ + c);
      float4 y = *(const float4*)(ea_t + (size_t)h * C_ + c);
      a.x += x.x * y.x; a.y += x.y * y.y; a.z += x.z * y.z; a.w += x.w * y.w;
    }
    a.x /= 12.f; a.y /= 12.f; a.z /= 12.f; a.w /= 12.f;
    v[q] = a;
    local += a.x + a.y + a.z + a.w;
  }
  float s = local;
#pragma unroll
  for (int m = 32; m > 0; m >>= 1) s += __shfl_xor(s, m);
  float S = s + 1e-5f;
#pragma unroll
  for (int q = 0; q < 4; ++q) {
    int c = t * 4 + 256 * q;
    float4 o;
    o.x = v[q].x / S; o.y = v[q].y / S; o.z = v[q].z / S; o.w = v[q].w / S;
    *(float4*)&ht[(size_t)np * C_ + c] = o;
  }
}

// ---------------------------------------------------------------- D: rs GEMM (R10 form)
__global__ void k_rs(const float* __restrict__ ht, const float* __restrict__ seq,
                     float* __restrict__ rs) {
  const int pt0 = blockIdx.x * 16;     // 200 tiles
  const int n = pt0 / P_;
  const int ot = threadIdx.x & 63;
  const int jt = threadIdx.x >> 6;     // 0..3
  const int o4 = blockIdx.y * 256 + ot * 4;
  __shared__ float hlds[16 * 66];
  float4 a32[4];
  double a64[4][4];
#pragma unroll
  for (int q = 0; q < 4; ++q) {
    a32[q] = {0.f, 0.f, 0.f, 0.f};
#pragma unroll
    for (int i = 0; i < 4; ++i) a64[q][i] = 0.0;
  }
  const float* seqn = seq + (size_t)n * C_ * D_;
  for (int c0 = 0; c0 < C_; c0 += 64) {
    for (int l = threadIdx.x; l < 1024; l += 256) {
      int j = l >> 6, cc = l & 63;
      hlds[j * 66 + cc] = ht[(size_t)(pt0 + j) * C_ + c0 + cc];
    }
    __syncthreads();
#pragma unroll 4
    for (int cc = 0; cc < 64; ++cc) {
      float4 sv = *(const float4*)&seqn[(size_t)(c0 + cc) * D_ + o4];
#pragma unroll
      for (int q = 0; q < 4; ++q) {
        float w = hlds[(jt * 4 + q) * 66 + cc];
        a32[q].x += w * sv.x; a32[q].y += w * sv.y;
        a32[q].z += w * sv.z; a32[q].w += w * sv.w;
      }
    }
#pragma unroll
    for (int q = 0; q < 4; ++q) {
      a64[q][0] += (double)a32[q].x; a64[q][1] += (double)a32[q].y;
      a64[q][2] += (double)a32[q].z; a64[q][3] += (double)a32[q].w;
      a32[q] = {0.f, 0.f, 0.f, 0.f};
    }
    __syncthreads();
  }
#pragma unroll
  for (int q = 0; q < 4; ++q) {
    int p = pt0 + jt * 4 + q;
#pragma unroll
    for (int i = 0; i < 4; ++i)
      rs[(size_t)p * D_ + o4 + i] = (float)a64[q][i];
  }
}

// ---------------------------------------------------------------- E: zh & zt, MERGED
// blockIdx.z selects the variant (0: Wh->zh double-tanh h-idx; 1: Wt->zt
// single-tanh t-idx). The two variants are mutually independent; merging puts
// 4800 waves in flight (4.7/SIMD) instead of two serial 2400-wave launches.
// Per-output instruction sequence unchanged -> zh/zt bit-identical.
__global__ void k_zht(const float* __restrict__ ent_emb, const float* __restrict__ rs,
                      const int* __restrict__ hts,
                      const float* __restrict__ Wh_, const float* __restrict__ bh_,
                      const float* __restrict__ Wt_, const float* __restrict__ bt_,
                      float* __restrict__ zh_, float* __restrict__ zt_) {
  const int which = blockIdx.z;        // 0 -> zh, 1 -> zt
  const float* W    = which ? Wt_ : Wh_;
  const float* bias = which ? bt_ : bh_;
  float* out        = which ? zt_ : zh_;
  const int dbl_tanh = which ^ 1;
  const int pt0 = blockIdx.x * 16;
  const int n = pt0 / P_;
  const int ot = threadIdx.x & 63;
  const int jt = threadIdx.x >> 6;
  const int o4 = blockIdx.y * 256 + ot * 4;
  __shared__ float xlds[16 * 66];
  __shared__ int sidx[16];
  if (threadIdx.x < 16) sidx[threadIdx.x] = hts[(pt0 + threadIdx.x) * 2 + which];
  float4 a32[4];
  double a64[4][4];
#pragma unroll
  for (int q = 0; q < 4; ++q) {
    a32[q] = {0.f, 0.f, 0.f, 0.f};
#pragma unroll
    for (int i = 0; i < 4; ++i) a64[q][i] = 0.0;
  }
  __syncthreads();
  for (int k0 = 0; k0 < IN2_; k0 += 64) {
    for (int l = threadIdx.x; l < 1024; l += 256) {
      int j = l >> 6, q = l & 63;
      int kx = k0 + q;
      float val;
      if (kx < D_) val = ent_emb[(size_t)(n * E_ + sidx[j]) * D_ + kx];
      else         val = rs[(size_t)(pt0 + j) * D_ + (kx - D_)];
      xlds[j * 66 + q] = val;
    }
    __syncthreads();
#pragma unroll 4
    for (int q = 0; q < 64; ++q) {
      float4 wv = *(const float4*)&W[(size_t)(k0 + q) * EMB_ + o4];
#pragma unroll
      for (int j = 0; j < 4; ++j) {
        float x = xlds[(jt * 4 + j) * 66 + q];
        a32[j].x += x * wv.x; a32[j].y += x * wv.y;
        a32[j].z += x * wv.z; a32[j].w += x * wv.w;
      }
    }
#pragma unroll
    for (int j = 0; j < 4; ++j) {
      a64[j][0] += (double)a32[j].x; a64[j][1] += (double)a32[j].y;
      a64[j][2] += (double)a32[j].z; a64[j][3] += (double)a32[j].w;
      a32[j] = {0.f, 0.f, 0.f, 0.f};
    }
    __syncthreads();
  }
#pragma unroll
  for (int j = 0; j < 4; ++j) {
    int p = pt0 + jt * 4 + j;
#pragma unroll
    for (int i = 0; i < 4; ++i) {
      int o = o4 + i;
      double z = a64[j][i] + (double)bias[o];
      z = tanh(z);
      if (dbl_tanh) z = tanh(z);
      out[(size_t)p * EMB_ + o] = (float)z;
    }
  }
}

// ---------------------------------------------------------------- F: logits partial (all 97 r)
// R12 form (best measured: 597 us): j=4 pairs/thread -> 4800 waves (4.7/SIMD);
// single-buffer Wlin (24.8 KB -> 6 blk/CU). #pragma unroll 1 pins codegen
// (R11 pathology: full unroll + hoist -> VGPR 256 + spill). Scalar FMA;
// per-output summation order (c asc within b, b asc) identical to rounds
// 4-13 -> partials bit-identical. r=96 folded in.
__global__ __launch_bounds__(256) void k_logits_part(
    const float* __restrict__ zh, const float* __restrict__ zt,
    const float* __restrict__ Wb, float* __restrict__ part) {
  const int bid = blockIdx.x;          // 0..1199
  const int s   = bid % 24;            // slab = k*2+bh  (XCD s%8 affinity)
  const int t   = bid / 24;            // p-tile 0..49
  const int k   = s >> 1, bh = s & 1;
  const int pt0 = t * 64;
  const int rt = threadIdx.x & 15;
  const int pg = threadIdx.x >> 4;     // 0..15 -> pairs pg*4+j
  const int kb0 = k * 64 + bh * 32;

  __shared__ float Wlin[64 * 97];      // 24832 B -> 6 blk/CU LDS cap

  // stage slice b (1552 float4 = 6 x 256 + 16 tail)
  auto stage_w = [&](int b) {
    const float* src = Wb + (size_t)(kb0 + b) * 6208;
#pragma unroll
    for (int u = 0; u < 6; ++u)
      GLOAD_LDS16(src + (u * 256 + threadIdx.x) * 4,
                  Wlin + (u * 256 + threadIdx.x) * 4);
    if (threadIdx.x < 16)
      GLOAD_LDS16(src + (1536 + threadIdx.x) * 4,
                  Wlin + (1536 + threadIdx.x) * 4);
  };

  stage_w(0);

  float acc[4][6];
  float acc6[4];
#pragma unroll
  for (int j = 0; j < 4; ++j) {
    acc6[j] = 0.f;
#pragma unroll
    for (int i = 0; i < 6; ++i) acc[j][i] = 0.f;
  }

  const float* ztb  = zt + (size_t)(pt0 + pg * 4) * EMB_ + k * 64;
  const float* zh_g = zh + (size_t)(pt0 + pg * 4) * EMB_ + kb0;

  __syncthreads();                     // drains vmcnt: Wlin(b=0) ready

#pragma unroll 1
  for (int b = 0; b < 32; ++b) {
    float zhv[4];
#pragma unroll
    for (int j = 0; j < 4; ++j) zhv[j] = zh_g[(size_t)j * EMB_ + b];

#pragma unroll 1
    for (int c0 = 0; c0 < 64; c0 += 4) {
      float4 ztv[4];
#pragma unroll
      for (int j = 0; j < 4; ++j)
        ztv[j] = *(const float4*)(ztb + (size_t)j * EMB_ + c0);
      float4 pz[4];
#pragma unroll
      for (int j = 0; j < 4; ++j) {
        pz[j].x = zhv[j] * ztv[j].x; pz[j].y = zhv[j] * ztv[j].y;
        pz[j].z = zhv[j] * ztv[j].z; pz[j].w = zhv[j] * ztv[j].w;
      }
#pragma unroll
      for (int cc = 0; cc < 4; ++cc) {
        const float* wr = &Wlin[(c0 + cc) * 97];
        float w6 = wr[96];
#pragma unroll
        for (int i = 0; i < 6; ++i) {
          float w = wr[rt + 16 * i];   // compiler ds_read_b32, 16-lane broadcast
#pragma unroll
          for (int j = 0; j < 4; ++j) {
            float pzc = (cc == 0) ? pz[j].x : (cc == 1) ? pz[j].y
                      : (cc == 2) ? pz[j].z : pz[j].w;
            acc[j][i] += pzc * w;
          }
        }
#pragma unroll
        for (int j = 0; j < 4; ++j) {
          float pzc = (cc == 0) ? pz[j].x : (cc == 1) ? pz[j].y
                    : (cc == 2) ? pz[j].z : pz[j].w;
          acc6[j] += pzc * w6;
        }
      }
    }
    if (b < 31) {
      __syncthreads();                 // readers of Wlin(b) done
      stage_w(b + 1);
      __syncthreads();                 // drains vmcnt: Wlin(b+1) ready
    }
  }

  float* po = part + (size_t)s * NP_ * NREL_;
#pragma unroll
  for (int j = 0; j < 4; ++j) {
    int p = pt0 + pg * 4 + j;
#pragma unroll
    for (int i = 0; i < 6; ++i)
      po[(size_t)p * NREL_ + rt + 16 * i] = acc[j][i];
    if (rt == 0) po[(size_t)p * NREL_ + 96] = acc6[j];
  }
}

// ---------------------------------------------------------------- G: finalize
__global__ void k_final(const float* __restrict__ part, const float* __restrict__ bb,
                        float* __restrict__ out) {
  const int p = blockIdx.x;
  const int r = threadIdx.x;           // 128 threads
  __shared__ double th_s;
  __shared__ int cnt[128];
  double v = 0.0;
  if (r < NREL_) {
#pragma unroll
    for (int g = 0; g < NPART; ++g)
      v += (double)part[(size_t)g * NP_ * NREL_ + (size_t)p * NREL_ + r];
    v += (double)bb[r];
    out[(size_t)p * NREL_ + r] = (float)v;
  }
  if (r == 0) th_s = v;
  __syncthreads();
  int pred = (r >= 1 && r < NREL_ && v > th_s) ? 1 : 0;
  cnt[r] = pred;
  __syncthreads();
  for (int s = 64; s > 0; s >>= 1) {
    if (r < s) cnt[r] += cnt[r + s];
    __syncthreads();
  }
  if (r < NREL_) {
    float pv = (r == 0) ? ((cnt[0] == 0) ? 1.f : 0.f) : (float)pred;
    out[(size_t)NP_ * NREL_ + (size_t)p * NREL_ + r] = pv;
  }
}

extern "C" void kernel_launch(void* const* d_in, const int* in_sizes, int n_in,
                              void* d_out, int out_size, void* d_ws, size_t ws_size,
                              hipStream_t stream) {
  const float* seq  = (const float*)d_in[0];
  const float* att  = (const float*)d_in[1];
  const int*   mpos = (const int*)d_in[2];
  const int*   hts  = (const int*)d_in[3];
  const float* Wh   = (const float*)d_in[4];
  const float* bh   = (const float*)d_in[5];
  const float* Wt   = (const float*)d_in[6];
  const float* bt   = (const float*)d_in[7];
  const float* Wb   = (const float*)d_in[8];
  const float* bb   = (const float*)d_in[9];
  float* out = (float*)d_out;
  float* ws = (float*)d_ws;

  float* ent_emb = ws;                   // [0, 122880)
  float* ent_att = ws + 122880;          // dead after k_ht_att
  float* ht      = ws + 2088960;         // dead after k_rs
  float* rs      = ws + 5365760;         // dead after k_zht
  float* zh      = ws + 7823360;
  float* zt      = ws + 10280960;
  // part (24*3200*97 floats) aliases dead ent_att+ht+rs: [122880, 7572480)
  float* part    = ws + 122880;

  k_ent_emb<<<160, 256, 0, stream>>>(seq, mpos, ent_emb);
  k_ent_att<<<7680, 256, 0, stream>>>(att, mpos, ent_att);
  k_ht_att<<<3200, 64, 0, stream>>>(ent_att, hts, ht);
  k_rs<<<dim3(200, 3), 256, 0, stream>>>(ht, seq, rs);
  k_zht<<<dim3(200, 3, 2), 256, 0, stream>>>(ent_emb, rs, hts, Wh, bh, Wt, bt, zh, zt);
  k_logits_part<<<1200, 256, 0, stream>>>(zh, zt, Wb, part);
  k_final<<<3200, 128, 0, stream>>>(part, bb, out);
}